// Round 11
// baseline (168.938 us; speedup 1.0000x reference)
//
#include <hip/hip_runtime.h>

typedef __bf16 bf16_t;
typedef __bf16 bf16x4 __attribute__((ext_vector_type(4)));
typedef __bf16 bf16x8 __attribute__((ext_vector_type(8)));
typedef float  f32x4  __attribute__((ext_vector_type(4)));

typedef const __attribute__((address_space(1))) void gvoid_t;
typedef __attribute__((address_space(3))) void lvoid_t;

#define N_NODES 8192
#define FEAT    1024
#define NCLS    64
#define TK      32

// ---- wave-wide min reductions via DPP (result broadcast via readlane 63) ----
__device__ __forceinline__ float wave_min_f32(float v) {
  int x = __float_as_int(v), t;
#define STEPF(ctrl) t = __builtin_amdgcn_update_dpp(x, x, ctrl, 0xf, 0xf, false); \
                    v = fminf(v, __int_as_float(t)); x = __float_as_int(v);
  STEPF(0x111)  // row_shr:1
  STEPF(0x112)  // row_shr:2
  STEPF(0x114)  // row_shr:4
  STEPF(0x118)  // row_shr:8
  STEPF(0x142)  // row_bcast:15
  STEPF(0x143)  // row_bcast:31
#undef STEPF
  return __int_as_float(__builtin_amdgcn_readlane(x, 63));
}

__device__ __forceinline__ unsigned wave_min_u32(unsigned v) {
  int x = (int)v, t;
#define STEPU(ctrl) t = __builtin_amdgcn_update_dpp(x, x, ctrl, 0xf, 0xf, false); \
                    x = (int)((unsigned)x < (unsigned)t ? (unsigned)x : (unsigned)t);
  STEPU(0x111)
  STEPU(0x112)
  STEPU(0x114)
  STEPU(0x118)
  STEPU(0x142)
  STEPU(0x143)
#undef STEPU
  return (unsigned)__builtin_amdgcn_readlane(x, 63);
}

// ------- prep: blocks 0..2047 = x -> bf16 cvt; blocks 2048..2319 = W1/W2 transpose -------
__global__ __launch_bounds__(256) void prep_kernel(const float* __restrict__ W1,
                                                   bf16_t* __restrict__ W1t,
                                                   const float* __restrict__ W2,
                                                   bf16_t* __restrict__ W2t,
                                                   const float* __restrict__ x,
                                                   bf16_t* __restrict__ x_bf) {
  const int tid = threadIdx.x;
  const int b = blockIdx.x;
  if (b < 2048) {
    // cvt: 8.39M floats, 2048 blocks x 256 thr x 4 float4
#pragma unroll
    for (int i = 0; i < 4; ++i) {
      const int idx = b * 1024 + i * 256 + tid;
      const float4 v = ((const float4*)x)[idx];
      bf16x4 o;
      o[0] = (__bf16)v.x; o[1] = (__bf16)v.y; o[2] = (__bf16)v.z; o[3] = (__bf16)v.w;
      ((bf16x4*)x_bf)[idx] = o;
    }
    return;
  }
  __shared__ float tile[64][65];
  const int tb = b - 2048;             // 0..271
  const int bxi = tb % 17, by = tb / 17;
  const float* in;
  bf16_t* out;
  int cols, bx;
  if (bxi < 16) { in = W1; out = W1t; cols = FEAT; bx = bxi; }
  else          { in = W2; out = W2t; cols = NCLS; bx = 0; }
#pragma unroll
  for (int i = 0; i < 16; ++i) {
    int li = i * 256 + tid;
    int r = li >> 6, c = li & 63;
    tile[r][c] = in[(size_t)(by * 64 + r) * cols + bx * 64 + c];
  }
  __syncthreads();
#pragma unroll
  for (int i = 0; i < 16; ++i) {
    int li = i * 256 + tid;
    int r = li >> 6, c = li & 63;
    out[(size_t)(bx * 64 + r) * FEAT + by * 64 + c] = (__bf16)tile[c][r];
  }
}

// ---- fused: every 17th block = gemm1 tile (512 total, spread through dispatch
// so gemm MFMA work overlaps the HBM-bound adj scan); the rest = topk rows.
// 17 % 8 == 1 -> gemm block b=17j lands on XCD j%8: round-10 XCD mapping holds.
#define FUSED_BLOCKS (512 * 17)
__global__ __launch_bounds__(256, 2) void fused_kernel(const float* __restrict__ adj,
                                                       const float* __restrict__ alphap,
                                                       const bf16_t* __restrict__ x_bf,
                                                       const bf16_t* __restrict__ W1t,
                                                       bf16_t* __restrict__ xW1,
                                                       int* __restrict__ idx_out,
                                                       float* __restrict__ w_out) {
  constexpr int BM = 128, BN = 128, Kd = FEAT;
  constexpr int LDSA = BM * 64;
  constexpr int LDSB = BN * 64;
  __shared__ char smem[2 * (LDSA + LDSB)];   // 32 KB, shared by both branches
  const int tid = threadIdx.x;
  const int b = blockIdx.x;
  const int j = b / 17;

  if (b % 17 == 0) {
    // ================= gemm1 branch (round-10 kernel verbatim) =================
    auto lds = (char(*)[LDSA + LDSB])smem;
    const int wid = tid >> 6, lane = tid & 63;
    const int xcd = j & 7, jj = j >> 3;            // jj in 0..63
    const int bm0 = (xcd * 8 + (jj >> 3)) * BM;    // 8 M-tiles per XCD band
    const int bn0 = (jj & 7) * BN;
    const int wr = wid >> 1, wc = wid & 1;
    constexpr int WM = BM / 2, WN = BN / 2;
    constexpr int NMI = WM / 16, NNI = WN / 16;

    auto stage = [&](int buf, int t) {
      const int k0 = t * 32;
#pragma unroll
      for (int li = 0; li < BM / 64; ++li) {
        const int rb = wid * (BM / 4) + li * 16;
        const int r = rb + (lane >> 2);
        const int sdat = (lane & 3) ^ (r & 3);
        const bf16_t* g = x_bf + (size_t)(bm0 + r) * Kd + k0 + sdat * 8;
        __builtin_amdgcn_global_load_lds((gvoid_t*)g, (lvoid_t*)&lds[buf][rb * 64], 16, 0, 0);
      }
#pragma unroll
      for (int li = 0; li < BN / 64; ++li) {
        const int rb = wid * (BN / 4) + li * 16;
        const int r = rb + (lane >> 2);
        const int sdat = (lane & 3) ^ (r & 3);
        const bf16_t* g = W1t + (size_t)(bn0 + r) * Kd + k0 + sdat * 8;
        __builtin_amdgcn_global_load_lds((gvoid_t*)g, (lvoid_t*)&lds[buf][LDSA + rb * 64], 16, 0, 0);
      }
    };

    f32x4 acc[NMI][NNI];
#pragma unroll
    for (int mi = 0; mi < NMI; ++mi)
#pragma unroll
      for (int ni = 0; ni < NNI; ++ni) acc[mi][ni] = (f32x4){0.f, 0.f, 0.f, 0.f};

    const int nT = Kd / 32;
    stage(0, 0);
    __syncthreads();
    for (int t = 0; t < nT; ++t) {
      const int cur = t & 1;
      if (t + 1 < nT) stage(cur ^ 1, t + 1);
      const char* la = &lds[cur][0];
      const char* lb = &lds[cur][LDSA];
      const int s = lane >> 4;
      bf16x8 af[NMI], bfr[NNI];
#pragma unroll
      for (int mi = 0; mi < NMI; ++mi) {
        const int m = wr * WM + mi * 16 + (lane & 15);
        af[mi] = *(const bf16x8*)(la + m * 64 + ((s ^ (m & 3)) * 16));
      }
#pragma unroll
      for (int ni = 0; ni < NNI; ++ni) {
        const int n = wc * WN + ni * 16 + (lane & 15);
        bfr[ni] = *(const bf16x8*)(lb + n * 64 + ((s ^ (n & 3)) * 16));
      }
#pragma unroll
      for (int mi = 0; mi < NMI; ++mi)
#pragma unroll
        for (int ni = 0; ni < NNI; ++ni)
          acc[mi][ni] = __builtin_amdgcn_mfma_f32_16x16x32_bf16(af[mi], bfr[ni], acc[mi][ni], 0, 0, 0);
      __syncthreads();
    }

#pragma unroll
    for (int mi = 0; mi < NMI; ++mi)
#pragma unroll
      for (int ni = 0; ni < NNI; ++ni)
#pragma unroll
        for (int j4 = 0; j4 < 4; ++j4) {
          const int r = bm0 + wr * WM + mi * 16 + (lane >> 4) * 4 + j4;
          const int c = bn0 + wc * WN + ni * 16 + (lane & 15);
          xW1[(size_t)r * FEAT + c] = (__bf16)acc[mi][ni][j4];
        }
    return;
  }

  // ================= topk branch =================
  float* svals = (float*)smem;
  int*   sidx  = (int*)(smem + 1024);
  int*   scnt  = (int*)(smem + 2048);
  const int row = b - j - 1;                 // non-gemm ordinal
  const float* arow = adj + (size_t)row * N_NODES;
  float thr = 1.0f / 128.0f;  // E[count]=64 for uniform[0,1)
  int cnt = 0;
  for (int attempt = 0; attempt < 24; ++attempt) {
    __syncthreads();
    if (tid == 0) *scnt = 0;
    __syncthreads();
#pragma unroll
    for (int v = 0; v < 8; ++v) {
      int vi = v * 256 + tid;
      float4 q = ((const float4*)arow)[vi];
      int base = vi * 4;
      if (q.x < thr) { int p = atomicAdd(scnt, 1); if (p < 256) { svals[p] = q.x; sidx[p] = base;     } }
      if (q.y < thr) { int p = atomicAdd(scnt, 1); if (p < 256) { svals[p] = q.y; sidx[p] = base + 1; } }
      if (q.z < thr) { int p = atomicAdd(scnt, 1); if (p < 256) { svals[p] = q.z; sidx[p] = base + 2; } }
      if (q.w < thr) { int p = atomicAdd(scnt, 1); if (p < 256) { svals[p] = q.w; sidx[p] = base + 3; } }
    }
    __syncthreads();
    cnt = *scnt;
    if (cnt >= TK && cnt <= 256) break;  // exact: all K smallest are < thr
    thr = (cnt < TK) ? thr * 2.0f : thr * 0.5f;
  }
  const int M = cnt < 256 ? cnt : 256;

  if (tid < 64) {
    const int lane = tid;
    const float INF = __int_as_float(0x7f800000);
    float cv[4];
    int   ci[4];
#pragma unroll
    for (int jq = 0; jq < 4; ++jq) {
      int slot = lane + jq * 64;
      if (slot < M) { cv[jq] = svals[slot]; ci[jq] = sidx[slot]; }
      else          { cv[jq] = INF;         ci[jq] = 0x7fffffff; }
    }
    float selv = 0.f;
    int   seli = 0;
    for (int k = 0; k < TK; ++k) {
      const float lv = fminf(fminf(cv[0], cv[1]), fminf(cv[2], cv[3]));
      const float wv = wave_min_f32(lv);
      unsigned li = 0xffffffffu;
#pragma unroll
      for (int jq = 0; jq < 4; ++jq)
        if (cv[jq] == wv) li = li < (unsigned)ci[jq] ? li : (unsigned)ci[jq];
      const unsigned wi = wave_min_u32(li);
      if (lane == k) { selv = wv; seli = (int)wi; }
#pragma unroll
      for (int jq = 0; jq < 4; ++jq)
        if (cv[jq] == wv && (unsigned)ci[jq] == wi) cv[jq] = INF;
    }
    const float a = alphap[0];
    const float e = (lane < TK) ? expf(-a * selv) : 0.0f;
    float ssum = e;
#pragma unroll
    for (int off = 1; off < 64; off <<= 1) ssum += __shfl_xor(ssum, off);
    if (lane < TK) {
      idx_out[(size_t)row * TK + lane] = seli & (N_NODES - 1);
      w_out[(size_t)row * TK + lane]   = e / ssum;
    }
  }
}

// ------- fused spmm1+bias+relu+gemm2, 8-way feature-split for L2 locality -------
#define SROWS  16
#define SCHUNK 128
#define NCHUNK 8
__global__ __launch_bounds__(256) void spmm_gemm2_kernel(const bf16_t* __restrict__ xW1,
                                                         const int* __restrict__ idxm,
                                                         const float* __restrict__ wm,
                                                         const float* __restrict__ b1,
                                                         const bf16_t* __restrict__ W2t,
                                                         bf16_t* __restrict__ part) {
  const int tid = threadIdx.x;
  const int c  = blockIdx.x & (NCHUNK - 1);
  const int rg = blockIdx.x >> 3;
  const int r0 = rg * SROWS;
  const int f0 = c * SCHUNK;
  __shared__ int    snb[SROWS][TK];
  __shared__ float  swt[SROWS][TK];
  __shared__ bf16_t hls[SROWS][SCHUNK];  // XOR-swizzled groups of 8
  ((int2*)&snb[0][0])[tid]   = ((const int2*)(idxm + (size_t)r0 * TK))[tid];
  ((float2*)&swt[0][0])[tid] = ((const float2*)(wm + (size_t)r0 * TK))[tid];
  __syncthreads();
  const int wid = tid >> 6, lane = tid & 63;
  const int gr = tid >> 4;            // gather row 0..15
  const int gc = (tid & 15) * 8;      // feat base within chunk (8 feats/thread)

  float a[8];
#pragma unroll
  for (int j = 0; j < 8; ++j) a[j] = 0.f;
#pragma unroll 8
  for (int k = 0; k < TK; ++k) {
    const bf16x8 v = *(const bf16x8*)(xW1 + (size_t)snb[gr][k] * FEAT + f0 + gc);
    const float wk = swt[gr][k];
#pragma unroll
    for (int j = 0; j < 8; ++j) a[j] += wk * (float)v[j];
  }
  const float4 b0 = ((const float4*)(b1 + f0 + gc))[0];
  const float4 b1v = ((const float4*)(b1 + f0 + gc))[1];
  bf16x8 o0;
  o0[0] = (__bf16)fmaxf(a[0] + b0.x, 0.f);
  o0[1] = (__bf16)fmaxf(a[1] + b0.y, 0.f);
  o0[2] = (__bf16)fmaxf(a[2] + b0.z, 0.f);
  o0[3] = (__bf16)fmaxf(a[3] + b0.w, 0.f);
  o0[4] = (__bf16)fmaxf(a[4] + b1v.x, 0.f);
  o0[5] = (__bf16)fmaxf(a[5] + b1v.y, 0.f);
  o0[6] = (__bf16)fmaxf(a[6] + b1v.z, 0.f);
  o0[7] = (__bf16)fmaxf(a[7] + b1v.w, 0.f);
  const int g0 = (gc >> 3);           // group 0..15
  char* hb = (char*)&hls[0][0];
  *(bf16x8*)(hb + gr * (SCHUNK * 2) + ((g0 ^ (gr & 7)) * 16)) = o0;

  // prefetch W2t B-frags before the barrier (independent of LDS writes)
  const int s = lane >> 4;
  const int m = lane & 15;
  const int n = wid * 16 + (lane & 15);
  bf16x8 bfr[SCHUNK / 32];
#pragma unroll
  for (int ks = 0; ks < SCHUNK / 32; ++ks)
    bfr[ks] = *(const bf16x8*)(W2t + (size_t)n * FEAT + f0 + ks * 32 + s * 8);
  __syncthreads();

  // MFMA: out[16 x 64] K-partial (K=SCHUNK); this wave owns cols wid*16..
  f32x4 acc = (f32x4){0.f, 0.f, 0.f, 0.f};
  const char* hr = (char*)&hls[0][0] + m * (SCHUNK * 2);
#pragma unroll
  for (int ks = 0; ks < SCHUNK / 32; ++ks) {
    const int g = ks * 4 + s;
    const bf16x8 afrag = *(const bf16x8*)(hr + ((g ^ (m & 7)) * 16));
    acc = __builtin_amdgcn_mfma_f32_16x16x32_bf16(afrag, bfr[ks], acc, 0, 0, 0);
  }
#pragma unroll
  for (int j = 0; j < 4; ++j) {
    const int r = r0 + (lane >> 4) * 4 + j;
    const int col = wid * 16 + (lane & 15);
    part[((size_t)c * N_NODES + r) * NCLS + col] = (__bf16)acc[j];
  }
}

// ------- out2 = sum of 8 bf16 partials (fixed order, deterministic) -------
__global__ __launch_bounds__(256) void reduce8_kernel(const bf16_t* __restrict__ part,
                                                      float* __restrict__ out2) {
  const int i = blockIdx.x * 256 + threadIdx.x;   // over N*NCLS/8 bf16x8
  float s[8];
  {
    const bf16x8 p = ((const bf16x8*)part)[i];
#pragma unroll
    for (int j = 0; j < 8; ++j) s[j] = (float)p[j];
  }
#pragma unroll
  for (int c = 1; c < NCHUNK; ++c) {
    const bf16x8 p = ((const bf16x8*)(part + (size_t)c * N_NODES * NCLS))[i];
#pragma unroll
    for (int j = 0; j < 8; ++j) s[j] += (float)p[j];
  }
  float4 lo, hi;
  lo.x = s[0]; lo.y = s[1]; lo.z = s[2]; lo.w = s[3];
  hi.x = s[4]; hi.y = s[5]; hi.z = s[6]; hi.w = s[7];
  ((float4*)out2)[i * 2]     = lo;
  ((float4*)out2)[i * 2 + 1] = hi;
}

// ---------------- spmm2 + b2 + log_softmax: one wave per output row ----------------
__global__ __launch_bounds__(256) void final_kernel(const float* __restrict__ out2,
                                                    const int* __restrict__ idxm,
                                                    const float* __restrict__ wm,
                                                    const float* __restrict__ b2,
                                                    float* __restrict__ out) {
  const int wid = threadIdx.x >> 6, lane = threadIdx.x & 63;
  const int row = blockIdx.x * 4 + wid;
  const int kk = lane & 31;
  const float wv = wm[(size_t)row * TK + kk];
  const int   iv = idxm[(size_t)row * TK + kk];
  float acc = 0.f;
#pragma unroll 8
  for (int k = 0; k < TK; ++k) {
    const float wk = __shfl(wv, k);
    const int   ik = __shfl(iv, k);
    acc += wk * out2[(size_t)ik * NCLS + lane];
  }
  const float logit = acc + b2[lane];
  float m = logit;
#pragma unroll
  for (int off = 1; off < 64; off <<= 1) m = fmaxf(m, __shfl_xor(m, off));
  const float e = expf(logit - m);
  float ssum = e;
#pragma unroll
  for (int off = 1; off < 64; off <<= 1) ssum += __shfl_xor(ssum, off);
  out[(size_t)row * NCLS + lane] = (logit - m) - logf(ssum);
}

extern "C" void kernel_launch(void* const* d_in, const int* in_sizes, int n_in,
                              void* d_out, int out_size, void* d_ws, size_t ws_size,
                              hipStream_t stream) {
  (void)in_sizes; (void)n_in; (void)out_size; (void)ws_size;
  const float* x     = (const float*)d_in[0];
  const float* adj   = (const float*)d_in[1];
  const float* W1    = (const float*)d_in[2];
  const float* b1    = (const float*)d_in[3];
  const float* W2    = (const float*)d_in[4];
  const float* b2    = (const float*)d_in[5];
  const float* alpha = (const float*)d_in[6];

  char* ws = (char*)d_ws;
  const size_t MB = 1024 * 1024;
  bf16_t* x_bf = (bf16_t*)(ws + 0 * MB);    // 16 MB
  bf16_t* xW1  = (bf16_t*)(ws + 16 * MB);   // 16 MB
  bf16_t* W1t  = (bf16_t*)(ws + 48 * MB);   // 2 MB
  bf16_t* W2t  = (bf16_t*)(ws + 50 * MB);   // 128KB
  float*  out2 = (float*)(ws + 51 * MB);    // 2 MB
  int*    idxm = (int*)(ws + 53 * MB);      // 1 MB
  float*  wm   = (float*)(ws + 54 * MB);    // 1 MB
  bf16_t* part = (bf16_t*)(ws + 56 * MB);   // 8 MB: 8 x [8192][64] bf16 K-partials

  prep_kernel<<<dim3(2048 + 272), dim3(256), 0, stream>>>(W1, W1t, W2, W2t, x, x_bf);
  fused_kernel<<<dim3(FUSED_BLOCKS), dim3(256), 0, stream>>>(
      adj, alpha, x_bf, W1t, xW1, idxm, wm);
  spmm_gemm2_kernel<<<dim3((N_NODES / SROWS) * NCHUNK), dim3(256), 0, stream>>>(
      xW1, idxm, wm, b1, W2t, part);
  reduce8_kernel<<<dim3(N_NODES * NCLS / 8 / 256), dim3(256), 0, stream>>>(part, out2);
  final_kernel<<<dim3(N_NODES / 4), dim3(256), 0, stream>>>(out2, idxm, wm, b2, (float*)d_out);
}

// Round 13
// 131.688 us; speedup vs baseline: 1.2829x; 1.2829x over previous
//
#include <hip/hip_runtime.h>

typedef __bf16 bf16_t;
typedef __bf16 bf16x4 __attribute__((ext_vector_type(4)));
typedef __bf16 bf16x8 __attribute__((ext_vector_type(8)));
typedef float  f32x4  __attribute__((ext_vector_type(4)));

typedef const __attribute__((address_space(1))) void gvoid_t;
typedef __attribute__((address_space(3))) void lvoid_t;

#define N_NODES 8192
#define FEAT    1024
#define NCLS    64
#define TK      32

// ---- wave-wide min reductions via DPP (result broadcast via readlane 63) ----
__device__ __forceinline__ float wave_min_f32(float v) {
  int x = __float_as_int(v), t;
#define STEPF(ctrl) t = __builtin_amdgcn_update_dpp(x, x, ctrl, 0xf, 0xf, false); \
                    v = fminf(v, __int_as_float(t)); x = __float_as_int(v);
  STEPF(0x111)  // row_shr:1
  STEPF(0x112)  // row_shr:2
  STEPF(0x114)  // row_shr:4
  STEPF(0x118)  // row_shr:8
  STEPF(0x142)  // row_bcast:15
  STEPF(0x143)  // row_bcast:31
#undef STEPF
  return __int_as_float(__builtin_amdgcn_readlane(x, 63));
}

__device__ __forceinline__ unsigned wave_min_u32(unsigned v) {
  int x = (int)v, t;
#define STEPU(ctrl) t = __builtin_amdgcn_update_dpp(x, x, ctrl, 0xf, 0xf, false); \
                    x = (int)((unsigned)x < (unsigned)t ? (unsigned)x : (unsigned)t);
  STEPU(0x111)
  STEPU(0x112)
  STEPU(0x114)
  STEPU(0x118)
  STEPU(0x142)
  STEPU(0x143)
#undef STEPU
  return (unsigned)__builtin_amdgcn_readlane(x, 63);
}

// ------- topk (blocks < N_NODES) + merged W1/W2 transpose (blocks >= N_NODES) -------
__global__ __launch_bounds__(256) void topk_kernel(const float* __restrict__ adj,
                                                   const float* __restrict__ alphap,
                                                   const float* __restrict__ x,
                                                   bf16_t* __restrict__ x_bf,
                                                   int* __restrict__ idx_out,
                                                   float* __restrict__ w_out,
                                                   const float* __restrict__ W1,
                                                   bf16_t* __restrict__ W1t,
                                                   const float* __restrict__ W2,
                                                   bf16_t* __restrict__ W2t) {
  const int tid = threadIdx.x;
  __shared__ float tile[64][65];
  __shared__ float svals[256];
  __shared__ int   sidx[256];
  __shared__ int   scnt;

  if (blockIdx.x >= N_NODES) {
    // ---- transpose+convert branch ----
    const int tb = blockIdx.x - N_NODES;   // 0..271
    const int bxi = tb % 17, by = tb / 17;
    const float* in;
    bf16_t* out;
    int cols, bx;
    if (bxi < 16) { in = W1; out = W1t; cols = FEAT; bx = bxi; }
    else          { in = W2; out = W2t; cols = NCLS; bx = 0; }
#pragma unroll
    for (int i = 0; i < 16; ++i) {
      int li = i * 256 + tid;
      int r = li >> 6, c = li & 63;
      tile[r][c] = in[(size_t)(by * 64 + r) * cols + bx * 64 + c];
    }
    __syncthreads();
#pragma unroll
    for (int i = 0; i < 16; ++i) {
      int li = i * 256 + tid;
      int r = li >> 6, c = li & 63;
      out[(size_t)(bx * 64 + r) * FEAT + by * 64 + c] = (__bf16)tile[c][r];
    }
    return;
  }

  const int row = blockIdx.x;
  {
    const float4 v = ((const float4*)(x + (size_t)row * FEAT))[tid];
    bf16x4 o;
    o[0] = (__bf16)v.x; o[1] = (__bf16)v.y; o[2] = (__bf16)v.z; o[3] = (__bf16)v.w;
    ((bf16x4*)(x_bf + (size_t)row * FEAT))[tid] = o;
  }

  const float* arow = adj + (size_t)row * N_NODES;
  float thr = 1.0f / 128.0f;  // E[count]=64 for uniform[0,1)
  int cnt = 0;
  for (int attempt = 0; attempt < 24; ++attempt) {
    __syncthreads();
    if (tid == 0) scnt = 0;
    __syncthreads();
#pragma unroll
    for (int v = 0; v < 8; ++v) {
      int vi = v * 256 + tid;
      const f32x4 q = __builtin_nontemporal_load(&((const f32x4*)arow)[vi]);
      int base = vi * 4;
      if (q[0] < thr) { int p = atomicAdd(&scnt, 1); if (p < 256) { svals[p] = q[0]; sidx[p] = base;     } }
      if (q[1] < thr) { int p = atomicAdd(&scnt, 1); if (p < 256) { svals[p] = q[1]; sidx[p] = base + 1; } }
      if (q[2] < thr) { int p = atomicAdd(&scnt, 1); if (p < 256) { svals[p] = q[2]; sidx[p] = base + 2; } }
      if (q[3] < thr) { int p = atomicAdd(&scnt, 1); if (p < 256) { svals[p] = q[3]; sidx[p] = base + 3; } }
    }
    __syncthreads();
    cnt = scnt;
    if (cnt >= TK && cnt <= 256) break;  // exact: all K smallest are < thr
    thr = (cnt < TK) ? thr * 2.0f : thr * 0.5f;
  }
  const int M = cnt < 256 ? cnt : 256;

  if (tid < 64) {
    const int lane = tid;
    const float INF = __int_as_float(0x7f800000);
    float cv[4];
    int   ci[4];
#pragma unroll
    for (int j = 0; j < 4; ++j) {
      int slot = lane + j * 64;
      if (slot < M) { cv[j] = svals[slot]; ci[j] = sidx[slot]; }
      else          { cv[j] = INF;         ci[j] = 0x7fffffff; }
    }
    float selv = 0.f;
    int   seli = 0;
    for (int k = 0; k < TK; ++k) {
      const float lv = fminf(fminf(cv[0], cv[1]), fminf(cv[2], cv[3]));
      const float wv = wave_min_f32(lv);
      unsigned li = 0xffffffffu;
#pragma unroll
      for (int j = 0; j < 4; ++j)
        if (cv[j] == wv) li = li < (unsigned)ci[j] ? li : (unsigned)ci[j];
      const unsigned wi = wave_min_u32(li);
      if (lane == k) { selv = wv; seli = (int)wi; }
#pragma unroll
      for (int j = 0; j < 4; ++j)
        if (cv[j] == wv && (unsigned)ci[j] == wi) cv[j] = INF;
    }
    const float a = alphap[0];
    const float e = (lane < TK) ? expf(-a * selv) : 0.0f;
    float ssum = e;
#pragma unroll
    for (int off = 1; off < 64; off <<= 1) ssum += __shfl_xor(ssum, off);
    if (lane < TK) {
      idx_out[(size_t)row * TK + lane] = seli & (N_NODES - 1);
      w_out[(size_t)row * TK + lane]   = e / ssum;
    }
  }
}

// ---------------- bf16 MFMA GEMM: C = A * Bt^T, 128x128 tile ----------------
// 1D grid, XCD-band mapping: XCD c (= b%8, round-robin dispatch) owns M-tiles
// 8c..8c+7 x all 8 N-tiles -> stationary per-XCD set = 2MB A-band + 2MB B = L2.
__global__ __launch_bounds__(256, 2) void gemm1_kernel(const bf16_t* __restrict__ A,
                                                       const bf16_t* __restrict__ Bt,
                                                       bf16_t* __restrict__ C) {
  constexpr int BM = 128, BN = 128, Kd = FEAT;
  constexpr int LDSA = BM * 64;   // BM rows x 32 k x 2B
  constexpr int LDSB = BN * 64;
  __shared__ char lds[2][LDSA + LDSB];
  const int tid = threadIdx.x;
  const int wid = tid >> 6, lane = tid & 63;
  const int b = blockIdx.x;                      // 512 blocks
  const int xcd = b & 7, j = b >> 3;             // j in 0..63
  const int bm0 = (xcd * 8 + (j >> 3)) * BM;     // M-tile 0..63 (8 per XCD)
  const int bn0 = (j & 7) * BN;                  // N-tile 0..7
  const int wr = wid >> 1, wc = wid & 1;
  constexpr int WM = BM / 2, WN = BN / 2;
  constexpr int NMI = WM / 16, NNI = WN / 16;

  auto stage = [&](int buf, int t) {
    const int k0 = t * 32;
#pragma unroll
    for (int li = 0; li < BM / 64; ++li) {
      const int rb = wid * (BM / 4) + li * 16;
      const int r = rb + (lane >> 2);
      const int sdat = (lane & 3) ^ (r & 3);
      const bf16_t* g = A + (size_t)(bm0 + r) * Kd + k0 + sdat * 8;
      __builtin_amdgcn_global_load_lds((gvoid_t*)g, (lvoid_t*)&lds[buf][rb * 64], 16, 0, 0);
    }
#pragma unroll
    for (int li = 0; li < BN / 64; ++li) {
      const int rb = wid * (BN / 4) + li * 16;
      const int r = rb + (lane >> 2);
      const int sdat = (lane & 3) ^ (r & 3);
      const bf16_t* g = Bt + (size_t)(bn0 + r) * Kd + k0 + sdat * 8;
      __builtin_amdgcn_global_load_lds((gvoid_t*)g, (lvoid_t*)&lds[buf][LDSA + rb * 64], 16, 0, 0);
    }
  };

  f32x4 acc[NMI][NNI];
#pragma unroll
  for (int mi = 0; mi < NMI; ++mi)
#pragma unroll
    for (int ni = 0; ni < NNI; ++ni) acc[mi][ni] = (f32x4){0.f, 0.f, 0.f, 0.f};

  const int nT = Kd / 32;
  stage(0, 0);
  __syncthreads();
  for (int t = 0; t < nT; ++t) {
    const int cur = t & 1;
    if (t + 1 < nT) stage(cur ^ 1, t + 1);
    const char* la = &lds[cur][0];
    const char* lb = &lds[cur][LDSA];
    const int s = lane >> 4;
    bf16x8 af[NMI], bfr[NNI];
#pragma unroll
    for (int mi = 0; mi < NMI; ++mi) {
      const int m = wr * WM + mi * 16 + (lane & 15);
      af[mi] = *(const bf16x8*)(la + m * 64 + ((s ^ (m & 3)) * 16));
    }
#pragma unroll
    for (int ni = 0; ni < NNI; ++ni) {
      const int n = wc * WN + ni * 16 + (lane & 15);
      bfr[ni] = *(const bf16x8*)(lb + n * 64 + ((s ^ (n & 3)) * 16));
    }
#pragma unroll
    for (int mi = 0; mi < NMI; ++mi)
#pragma unroll
      for (int ni = 0; ni < NNI; ++ni)
        acc[mi][ni] = __builtin_amdgcn_mfma_f32_16x16x32_bf16(af[mi], bfr[ni], acc[mi][ni], 0, 0, 0);
    __syncthreads();
  }

#pragma unroll
  for (int mi = 0; mi < NMI; ++mi)
#pragma unroll
    for (int ni = 0; ni < NNI; ++ni)
#pragma unroll
      for (int j4 = 0; j4 < 4; ++j4) {
        const int r = bm0 + wr * WM + mi * 16 + (lane >> 4) * 4 + j4;
        const int c = bn0 + wc * WN + ni * 16 + (lane & 15);
        C[(size_t)r * FEAT + c] = (__bf16)acc[mi][ni][j4];
      }
}

// ------- fused spmm1+bias+relu+gemm2, 8-way feature-split for L2 locality -------
#define SROWS  16
#define SCHUNK 128
#define NCHUNK 8
__global__ __launch_bounds__(256) void spmm_gemm2_kernel(const bf16_t* __restrict__ xW1,
                                                         const int* __restrict__ idxm,
                                                         const float* __restrict__ wm,
                                                         const float* __restrict__ b1,
                                                         const bf16_t* __restrict__ W2t,
                                                         bf16_t* __restrict__ part) {
  const int tid = threadIdx.x;
  const int c  = blockIdx.x & (NCHUNK - 1);
  const int rg = blockIdx.x >> 3;
  const int r0 = rg * SROWS;
  const int f0 = c * SCHUNK;
  __shared__ int    snb[SROWS][TK];
  __shared__ float  swt[SROWS][TK];
  __shared__ bf16_t hls[SROWS][SCHUNK];  // XOR-swizzled groups of 8
  ((int2*)&snb[0][0])[tid]   = ((const int2*)(idxm + (size_t)r0 * TK))[tid];
  ((float2*)&swt[0][0])[tid] = ((const float2*)(wm + (size_t)r0 * TK))[tid];
  __syncthreads();
  const int wid = tid >> 6, lane = tid & 63;
  const int gr = tid >> 4;            // gather row 0..15
  const int gc = (tid & 15) * 8;      // feat base within chunk (8 feats/thread)

  float a[8];
#pragma unroll
  for (int j = 0; j < 8; ++j) a[j] = 0.f;
#pragma unroll 8
  for (int k = 0; k < TK; ++k) {
    const bf16x8 v = *(const bf16x8*)(xW1 + (size_t)snb[gr][k] * FEAT + f0 + gc);
    const float wk = swt[gr][k];
#pragma unroll
    for (int j = 0; j < 8; ++j) a[j] += wk * (float)v[j];
  }
  const float4 b0 = ((const float4*)(b1 + f0 + gc))[0];
  const float4 b1v = ((const float4*)(b1 + f0 + gc))[1];
  bf16x8 o0;
  o0[0] = (__bf16)fmaxf(a[0] + b0.x, 0.f);
  o0[1] = (__bf16)fmaxf(a[1] + b0.y, 0.f);
  o0[2] = (__bf16)fmaxf(a[2] + b0.z, 0.f);
  o0[3] = (__bf16)fmaxf(a[3] + b0.w, 0.f);
  o0[4] = (__bf16)fmaxf(a[4] + b1v.x, 0.f);
  o0[5] = (__bf16)fmaxf(a[5] + b1v.y, 0.f);
  o0[6] = (__bf16)fmaxf(a[6] + b1v.z, 0.f);
  o0[7] = (__bf16)fmaxf(a[7] + b1v.w, 0.f);
  const int g0 = (gc >> 3);           // group 0..15
  char* hb = (char*)&hls[0][0];
  *(bf16x8*)(hb + gr * (SCHUNK * 2) + ((g0 ^ (gr & 7)) * 16)) = o0;

  // prefetch W2t B-frags before the barrier (independent of LDS writes)
  const int s = lane >> 4;
  const int m = lane & 15;
  const int n = wid * 16 + (lane & 15);
  bf16x8 bfr[SCHUNK / 32];
#pragma unroll
  for (int ks = 0; ks < SCHUNK / 32; ++ks)
    bfr[ks] = *(const bf16x8*)(W2t + (size_t)n * FEAT + f0 + ks * 32 + s * 8);
  __syncthreads();

  // MFMA: out[16 x 64] K-partial (K=SCHUNK); this wave owns cols wid*16..
  f32x4 acc = (f32x4){0.f, 0.f, 0.f, 0.f};
  const char* hr = (char*)&hls[0][0] + m * (SCHUNK * 2);
#pragma unroll
  for (int ks = 0; ks < SCHUNK / 32; ++ks) {
    const int g = ks * 4 + s;
    const bf16x8 afrag = *(const bf16x8*)(hr + ((g ^ (m & 7)) * 16));
    acc = __builtin_amdgcn_mfma_f32_16x16x32_bf16(afrag, bfr[ks], acc, 0, 0, 0);
  }
#pragma unroll
  for (int j = 0; j < 4; ++j) {
    const int r = r0 + (lane >> 4) * 4 + j;
    const int col = wid * 16 + (lane & 15);
    part[((size_t)c * N_NODES + r) * NCLS + col] = (__bf16)acc[j];
  }
}

// ------- out2 = sum of 8 bf16 partials (fixed order, deterministic) -------
__global__ __launch_bounds__(256) void reduce8_kernel(const bf16_t* __restrict__ part,
                                                      float* __restrict__ out2) {
  const int i = blockIdx.x * 256 + threadIdx.x;   // over N*NCLS/8 bf16x8
  float s[8];
  {
    const bf16x8 p = ((const bf16x8*)part)[i];
#pragma unroll
    for (int j = 0; j < 8; ++j) s[j] = (float)p[j];
  }
#pragma unroll
  for (int c = 1; c < NCHUNK; ++c) {
    const bf16x8 p = ((const bf16x8*)(part + (size_t)c * N_NODES * NCLS))[i];
#pragma unroll
    for (int j = 0; j < 8; ++j) s[j] += (float)p[j];
  }
  float4 lo, hi;
  lo.x = s[0]; lo.y = s[1]; lo.z = s[2]; lo.w = s[3];
  hi.x = s[4]; hi.y = s[5]; hi.z = s[6]; hi.w = s[7];
  ((float4*)out2)[i * 2]     = lo;
  ((float4*)out2)[i * 2 + 1] = hi;
}

// ------- spmm2 + b2 + log_softmax: 2 rows per wave, 8 per block -------
__global__ __launch_bounds__(256) void final_kernel(const float* __restrict__ out2,
                                                    const int* __restrict__ idxm,
                                                    const float* __restrict__ wm,
                                                    const float* __restrict__ b2,
                                                    float* __restrict__ out) {
  const int wid = threadIdx.x >> 6, lane = threadIdx.x & 63;
  const int kk = lane & 31;
  const float b2v = b2[lane];
#pragma unroll
  for (int rr = 0; rr < 2; ++rr) {
    const int row = blockIdx.x * 8 + rr * 4 + wid;
    const float wv = wm[(size_t)row * TK + kk];
    const int   iv = idxm[(size_t)row * TK + kk];
    float acc = 0.f;
#pragma unroll 8
    for (int k = 0; k < TK; ++k) {
      const float wk = __shfl(wv, k);
      const int   ik = __shfl(iv, k);
      acc += wk * out2[(size_t)ik * NCLS + lane];
    }
    const float logit = acc + b2v;
    float m = logit;
#pragma unroll
    for (int off = 1; off < 64; off <<= 1) m = fmaxf(m, __shfl_xor(m, off));
    const float e = expf(logit - m);
    float ssum = e;
#pragma unroll
    for (int off = 1; off < 64; off <<= 1) ssum += __shfl_xor(ssum, off);
    __builtin_nontemporal_store((logit - m) - logf(ssum),
                                &out[(size_t)row * NCLS + lane]);
  }
}

extern "C" void kernel_launch(void* const* d_in, const int* in_sizes, int n_in,
                              void* d_out, int out_size, void* d_ws, size_t ws_size,
                              hipStream_t stream) {
  (void)in_sizes; (void)n_in; (void)out_size; (void)ws_size;
  const float* x     = (const float*)d_in[0];
  const float* adj   = (const float*)d_in[1];
  const float* W1    = (const float*)d_in[2];
  const float* b1    = (const float*)d_in[3];
  const float* W2    = (const float*)d_in[4];
  const float* b2    = (const float*)d_in[5];
  const float* alpha = (const float*)d_in[6];

  char* ws = (char*)d_ws;
  const size_t MB = 1024 * 1024;
  bf16_t* x_bf = (bf16_t*)(ws + 0 * MB);    // 16 MB
  bf16_t* xW1  = (bf16_t*)(ws + 16 * MB);   // 16 MB
  bf16_t* W1t  = (bf16_t*)(ws + 48 * MB);   // 2 MB
  bf16_t* W2t  = (bf16_t*)(ws + 50 * MB);   // 128KB
  float*  out2 = (float*)(ws + 51 * MB);    // 2 MB
  int*    idxm = (int*)(ws + 53 * MB);      // 1 MB
  float*  wm   = (float*)(ws + 54 * MB);    // 1 MB
  bf16_t* part = (bf16_t*)(ws + 56 * MB);   // 8 MB: 8 x [8192][64] bf16 K-partials

  topk_kernel<<<dim3(N_NODES + 272), dim3(256), 0, stream>>>(
      adj, alpha, x, x_bf, idxm, wm, W1, W1t, W2, W2t);
  gemm1_kernel<<<dim3(512), dim3(256), 0, stream>>>(x_bf, W1t, xW1);
  spmm_gemm2_kernel<<<dim3((N_NODES / SROWS) * NCHUNK), dim3(256), 0, stream>>>(
      xW1, idxm, wm, b1, W2t, part);
  reduce8_kernel<<<dim3(N_NODES * NCLS / 8 / 256), dim3(256), 0, stream>>>(part, out2);
  final_kernel<<<dim3(N_NODES / 8), dim3(256), 0, stream>>>(out2, idxm, wm, b2, (float*)d_out);
}

// Round 14
// 131.255 us; speedup vs baseline: 1.2871x; 1.0033x over previous
//
#include <hip/hip_runtime.h>

typedef __bf16 bf16_t;
typedef __bf16 bf16x4 __attribute__((ext_vector_type(4)));
typedef __bf16 bf16x8 __attribute__((ext_vector_type(8)));
typedef float  f32x4  __attribute__((ext_vector_type(4)));

typedef const __attribute__((address_space(1))) void gvoid_t;
typedef __attribute__((address_space(3))) void lvoid_t;

#define N_NODES 8192
#define FEAT    1024
#define NCLS    64
#define TK      32

// ---- wave-wide min reductions via DPP (result broadcast via readlane 63) ----
__device__ __forceinline__ float wave_min_f32(float v) {
  int x = __float_as_int(v), t;
#define STEPF(ctrl) t = __builtin_amdgcn_update_dpp(x, x, ctrl, 0xf, 0xf, false); \
                    v = fminf(v, __int_as_float(t)); x = __float_as_int(v);
  STEPF(0x111)  // row_shr:1
  STEPF(0x112)  // row_shr:2
  STEPF(0x114)  // row_shr:4
  STEPF(0x118)  // row_shr:8
  STEPF(0x142)  // row_bcast:15
  STEPF(0x143)  // row_bcast:31
#undef STEPF
  return __int_as_float(__builtin_amdgcn_readlane(x, 63));
}

__device__ __forceinline__ unsigned wave_min_u32(unsigned v) {
  int x = (int)v, t;
#define STEPU(ctrl) t = __builtin_amdgcn_update_dpp(x, x, ctrl, 0xf, 0xf, false); \
                    x = (int)((unsigned)x < (unsigned)t ? (unsigned)x : (unsigned)t);
  STEPU(0x111)
  STEPU(0x112)
  STEPU(0x114)
  STEPU(0x118)
  STEPU(0x142)
  STEPU(0x143)
#undef STEPU
  return (unsigned)__builtin_amdgcn_readlane(x, 63);
}

// ------- topk (blocks < N_NODES) + merged W1/W2 transpose (blocks >= N_NODES) -------
__global__ __launch_bounds__(256) void topk_kernel(const float* __restrict__ adj,
                                                   const float* __restrict__ alphap,
                                                   const float* __restrict__ x,
                                                   bf16_t* __restrict__ x_bf,
                                                   int* __restrict__ idx_out,
                                                   float* __restrict__ w_out,
                                                   const float* __restrict__ W1,
                                                   bf16_t* __restrict__ W1t,
                                                   const float* __restrict__ W2,
                                                   bf16_t* __restrict__ W2t) {
  const int tid = threadIdx.x;
  __shared__ float tile[64][65];
  __shared__ float svals[256];
  __shared__ int   sidx[256];
  __shared__ int   scnt;

  if (blockIdx.x >= N_NODES) {
    // ---- transpose+convert branch ----
    const int tb = blockIdx.x - N_NODES;   // 0..271
    const int bxi = tb % 17, by = tb / 17;
    const float* in;
    bf16_t* out;
    int cols, bx;
    if (bxi < 16) { in = W1; out = W1t; cols = FEAT; bx = bxi; }
    else          { in = W2; out = W2t; cols = NCLS; bx = 0; }
#pragma unroll
    for (int i = 0; i < 16; ++i) {
      int li = i * 256 + tid;
      int r = li >> 6, c = li & 63;
      tile[r][c] = in[(size_t)(by * 64 + r) * cols + bx * 64 + c];
    }
    __syncthreads();
#pragma unroll
    for (int i = 0; i < 16; ++i) {
      int li = i * 256 + tid;
      int r = li >> 6, c = li & 63;
      out[(size_t)(bx * 64 + r) * FEAT + by * 64 + c] = (__bf16)tile[c][r];
    }
    return;
  }

  const int row = blockIdx.x;
  {
    const float4 v = ((const float4*)(x + (size_t)row * FEAT))[tid];
    bf16x4 o;
    o[0] = (__bf16)v.x; o[1] = (__bf16)v.y; o[2] = (__bf16)v.z; o[3] = (__bf16)v.w;
    ((bf16x4*)(x_bf + (size_t)row * FEAT))[tid] = o;
  }

  const float* arow = adj + (size_t)row * N_NODES;
  float thr = 1.0f / 128.0f;  // E[count]=64 for uniform[0,1)
  int cnt = 0;
  for (int attempt = 0; attempt < 24; ++attempt) {
    __syncthreads();
    if (tid == 0) scnt = 0;
    __syncthreads();
#pragma unroll
    for (int v = 0; v < 8; ++v) {
      int vi = v * 256 + tid;
      const f32x4 q = __builtin_nontemporal_load(&((const f32x4*)arow)[vi]);
      int base = vi * 4;
      if (q[0] < thr) { int p = atomicAdd(&scnt, 1); if (p < 256) { svals[p] = q[0]; sidx[p] = base;     } }
      if (q[1] < thr) { int p = atomicAdd(&scnt, 1); if (p < 256) { svals[p] = q[1]; sidx[p] = base + 1; } }
      if (q[2] < thr) { int p = atomicAdd(&scnt, 1); if (p < 256) { svals[p] = q[2]; sidx[p] = base + 2; } }
      if (q[3] < thr) { int p = atomicAdd(&scnt, 1); if (p < 256) { svals[p] = q[3]; sidx[p] = base + 3; } }
    }
    __syncthreads();
    cnt = scnt;
    if (cnt >= TK && cnt <= 256) break;  // exact: all K smallest are < thr
    thr = (cnt < TK) ? thr * 2.0f : thr * 0.5f;
  }
  const int M = cnt < 256 ? cnt : 256;

  if (tid < 64) {
    const int lane = tid;
    const float INF = __int_as_float(0x7f800000);
    float cv[4];
    int   ci[4];
#pragma unroll
    for (int j = 0; j < 4; ++j) {
      int slot = lane + j * 64;
      if (slot < M) { cv[j] = svals[slot]; ci[j] = sidx[slot]; }
      else          { cv[j] = INF;         ci[j] = 0x7fffffff; }
    }
    float selv = 0.f;
    int   seli = 0;
    for (int k = 0; k < TK; ++k) {
      const float lv = fminf(fminf(cv[0], cv[1]), fminf(cv[2], cv[3]));
      const float wv = wave_min_f32(lv);
      unsigned li = 0xffffffffu;
#pragma unroll
      for (int j = 0; j < 4; ++j)
        if (cv[j] == wv) li = li < (unsigned)ci[j] ? li : (unsigned)ci[j];
      const unsigned wi = wave_min_u32(li);
      if (lane == k) { selv = wv; seli = (int)wi; }
#pragma unroll
      for (int j = 0; j < 4; ++j)
        if (cv[j] == wv && (unsigned)ci[j] == wi) cv[j] = INF;
    }
    const float a = alphap[0];
    const float e = (lane < TK) ? expf(-a * selv) : 0.0f;
    float ssum = e;
#pragma unroll
    for (int off = 1; off < 64; off <<= 1) ssum += __shfl_xor(ssum, off);
    if (lane < TK) {
      idx_out[(size_t)row * TK + lane] = seli & (N_NODES - 1);
      w_out[(size_t)row * TK + lane]   = e / ssum;
    }
  }
}

// ---------------- bf16 MFMA GEMM: C = A * Bt^T, 128x128 tile ----------------
// 1D grid, XCD-band mapping: XCD c (= b%8, round-robin dispatch) owns M-tiles
// 8c..8c+7 x all 8 N-tiles -> stationary per-XCD set = 2MB A-band + 2MB B = L2.
__global__ __launch_bounds__(256, 2) void gemm1_kernel(const bf16_t* __restrict__ A,
                                                       const bf16_t* __restrict__ Bt,
                                                       bf16_t* __restrict__ C) {
  constexpr int BM = 128, BN = 128, Kd = FEAT;
  constexpr int LDSA = BM * 64;   // BM rows x 32 k x 2B
  constexpr int LDSB = BN * 64;
  __shared__ char lds[2][LDSA + LDSB];
  const int tid = threadIdx.x;
  const int wid = tid >> 6, lane = tid & 63;
  const int b = blockIdx.x;                      // 512 blocks
  const int xcd = b & 7, j = b >> 3;             // j in 0..63
  const int bm0 = (xcd * 8 + (j >> 3)) * BM;     // M-tile 0..63 (8 per XCD)
  const int bn0 = (j & 7) * BN;                  // N-tile 0..7
  const int wr = wid >> 1, wc = wid & 1;
  constexpr int WM = BM / 2, WN = BN / 2;
  constexpr int NMI = WM / 16, NNI = WN / 16;

  auto stage = [&](int buf, int t) {
    const int k0 = t * 32;
#pragma unroll
    for (int li = 0; li < BM / 64; ++li) {
      const int rb = wid * (BM / 4) + li * 16;
      const int r = rb + (lane >> 2);
      const int sdat = (lane & 3) ^ (r & 3);
      const bf16_t* g = A + (size_t)(bm0 + r) * Kd + k0 + sdat * 8;
      __builtin_amdgcn_global_load_lds((gvoid_t*)g, (lvoid_t*)&lds[buf][rb * 64], 16, 0, 0);
    }
#pragma unroll
    for (int li = 0; li < BN / 64; ++li) {
      const int rb = wid * (BN / 4) + li * 16;
      const int r = rb + (lane >> 2);
      const int sdat = (lane & 3) ^ (r & 3);
      const bf16_t* g = Bt + (size_t)(bn0 + r) * Kd + k0 + sdat * 8;
      __builtin_amdgcn_global_load_lds((gvoid_t*)g, (lvoid_t*)&lds[buf][LDSA + rb * 64], 16, 0, 0);
    }
  };

  f32x4 acc[NMI][NNI];
#pragma unroll
  for (int mi = 0; mi < NMI; ++mi)
#pragma unroll
    for (int ni = 0; ni < NNI; ++ni) acc[mi][ni] = (f32x4){0.f, 0.f, 0.f, 0.f};

  const int nT = Kd / 32;
  stage(0, 0);
  __syncthreads();
  for (int t = 0; t < nT; ++t) {
    const int cur = t & 1;
    if (t + 1 < nT) stage(cur ^ 1, t + 1);
    const char* la = &lds[cur][0];
    const char* lb = &lds[cur][LDSA];
    const int s = lane >> 4;
    bf16x8 af[NMI], bfr[NNI];
#pragma unroll
    for (int mi = 0; mi < NMI; ++mi) {
      const int m = wr * WM + mi * 16 + (lane & 15);
      af[mi] = *(const bf16x8*)(la + m * 64 + ((s ^ (m & 3)) * 16));
    }
#pragma unroll
    for (int ni = 0; ni < NNI; ++ni) {
      const int n = wc * WN + ni * 16 + (lane & 15);
      bfr[ni] = *(const bf16x8*)(lb + n * 64 + ((s ^ (n & 3)) * 16));
    }
#pragma unroll
    for (int mi = 0; mi < NMI; ++mi)
#pragma unroll
      for (int ni = 0; ni < NNI; ++ni)
        acc[mi][ni] = __builtin_amdgcn_mfma_f32_16x16x32_bf16(af[mi], bfr[ni], acc[mi][ni], 0, 0, 0);
    __syncthreads();
  }

#pragma unroll
  for (int mi = 0; mi < NMI; ++mi)
#pragma unroll
    for (int ni = 0; ni < NNI; ++ni)
#pragma unroll
      for (int j4 = 0; j4 < 4; ++j4) {
        const int r = bm0 + wr * WM + mi * 16 + (lane >> 4) * 4 + j4;
        const int c = bn0 + wc * WN + ni * 16 + (lane & 15);
        C[(size_t)r * FEAT + c] = (__bf16)acc[mi][ni][j4];
      }
}

// ------- fused spmm1+bias+relu+gemm2, 8-way feature-split for L2 locality -------
#define SROWS  16
#define SCHUNK 128
#define NCHUNK 8
__global__ __launch_bounds__(256) void spmm_gemm2_kernel(const bf16_t* __restrict__ xW1,
                                                         const int* __restrict__ idxm,
                                                         const float* __restrict__ wm,
                                                         const float* __restrict__ b1,
                                                         const bf16_t* __restrict__ W2t,
                                                         bf16_t* __restrict__ part) {
  const int tid = threadIdx.x;
  const int c  = blockIdx.x & (NCHUNK - 1);
  const int rg = blockIdx.x >> 3;
  const int r0 = rg * SROWS;
  const int f0 = c * SCHUNK;
  __shared__ int    snb[SROWS][TK];
  __shared__ float  swt[SROWS][TK];
  __shared__ bf16_t hls[SROWS][SCHUNK];  // XOR-swizzled groups of 8
  ((int2*)&snb[0][0])[tid]   = ((const int2*)(idxm + (size_t)r0 * TK))[tid];
  ((float2*)&swt[0][0])[tid] = ((const float2*)(wm + (size_t)r0 * TK))[tid];
  __syncthreads();
  const int wid = tid >> 6, lane = tid & 63;
  const int gr = tid >> 4;            // gather row 0..15
  const int gc = (tid & 15) * 8;      // feat base within chunk (8 feats/thread)

  float a[8];
#pragma unroll
  for (int j = 0; j < 8; ++j) a[j] = 0.f;
  // fully-unrolled gather: 32 independent 16B loads, deep vmcnt pipelining
#pragma unroll
  for (int k = 0; k < TK; ++k) {
    const bf16x8 v = *(const bf16x8*)(xW1 + (size_t)snb[gr][k] * FEAT + f0 + gc);
    const float wk = swt[gr][k];
#pragma unroll
    for (int j = 0; j < 8; ++j) a[j] += wk * (float)v[j];
  }
  const float4 b0 = ((const float4*)(b1 + f0 + gc))[0];
  const float4 b1v = ((const float4*)(b1 + f0 + gc))[1];
  bf16x8 o0;
  o0[0] = (__bf16)fmaxf(a[0] + b0.x, 0.f);
  o0[1] = (__bf16)fmaxf(a[1] + b0.y, 0.f);
  o0[2] = (__bf16)fmaxf(a[2] + b0.z, 0.f);
  o0[3] = (__bf16)fmaxf(a[3] + b0.w, 0.f);
  o0[4] = (__bf16)fmaxf(a[4] + b1v.x, 0.f);
  o0[5] = (__bf16)fmaxf(a[5] + b1v.y, 0.f);
  o0[6] = (__bf16)fmaxf(a[6] + b1v.z, 0.f);
  o0[7] = (__bf16)fmaxf(a[7] + b1v.w, 0.f);
  const int g0 = (gc >> 3);           // group 0..15
  char* hb = (char*)&hls[0][0];
  *(bf16x8*)(hb + gr * (SCHUNK * 2) + ((g0 ^ (gr & 7)) * 16)) = o0;

  // prefetch W2t B-frags before the barrier (independent of LDS writes)
  const int s = lane >> 4;
  const int m = lane & 15;
  const int n = wid * 16 + (lane & 15);
  bf16x8 bfr[SCHUNK / 32];
#pragma unroll
  for (int ks = 0; ks < SCHUNK / 32; ++ks)
    bfr[ks] = *(const bf16x8*)(W2t + (size_t)n * FEAT + f0 + ks * 32 + s * 8);
  __syncthreads();

  // MFMA: out[16 x 64] K-partial (K=SCHUNK); this wave owns cols wid*16..
  f32x4 acc = (f32x4){0.f, 0.f, 0.f, 0.f};
  const char* hr = (char*)&hls[0][0] + m * (SCHUNK * 2);
#pragma unroll
  for (int ks = 0; ks < SCHUNK / 32; ++ks) {
    const int g = ks * 4 + s;
    const bf16x8 afrag = *(const bf16x8*)(hr + ((g ^ (m & 7)) * 16));
    acc = __builtin_amdgcn_mfma_f32_16x16x32_bf16(afrag, bfr[ks], acc, 0, 0, 0);
  }
#pragma unroll
  for (int j = 0; j < 4; ++j) {
    const int r = r0 + (lane >> 4) * 4 + j;
    const int col = wid * 16 + (lane & 15);
    part[((size_t)c * N_NODES + r) * NCLS + col] = (__bf16)acc[j];
  }
}

// ------- out2 = sum of 8 bf16 partials (fixed order, deterministic) -------
__global__ __launch_bounds__(256) void reduce8_kernel(const bf16_t* __restrict__ part,
                                                      float* __restrict__ out2) {
  const int i = blockIdx.x * 256 + threadIdx.x;   // over N*NCLS/8 bf16x8
  float s[8];
  {
    const bf16x8 p = ((const bf16x8*)part)[i];
#pragma unroll
    for (int j = 0; j < 8; ++j) s[j] = (float)p[j];
  }
#pragma unroll
  for (int c = 1; c < NCHUNK; ++c) {
    const bf16x8 p = ((const bf16x8*)(part + (size_t)c * N_NODES * NCLS))[i];
#pragma unroll
    for (int j = 0; j < 8; ++j) s[j] += (float)p[j];
  }
  float4 lo, hi;
  lo.x = s[0]; lo.y = s[1]; lo.z = s[2]; lo.w = s[3];
  hi.x = s[4]; hi.y = s[5]; hi.z = s[6]; hi.w = s[7];
  ((float4*)out2)[i * 2]     = lo;
  ((float4*)out2)[i * 2 + 1] = hi;
}

// ------- spmm2 + b2 + log_softmax: 2 rows per wave, 8 per block -------
__global__ __launch_bounds__(256) void final_kernel(const float* __restrict__ out2,
                                                    const int* __restrict__ idxm,
                                                    const float* __restrict__ wm,
                                                    const float* __restrict__ b2,
                                                    float* __restrict__ out) {
  const int wid = threadIdx.x >> 6, lane = threadIdx.x & 63;
  const int kk = lane & 31;
  const float b2v = b2[lane];
#pragma unroll
  for (int rr = 0; rr < 2; ++rr) {
    const int row = blockIdx.x * 8 + rr * 4 + wid;
    const float wv = wm[(size_t)row * TK + kk];
    const int   iv = idxm[(size_t)row * TK + kk];
    float acc = 0.f;
#pragma unroll 8
    for (int k = 0; k < TK; ++k) {
      const float wk = __shfl(wv, k);
      const int   ik = __shfl(iv, k);
      acc += wk * out2[(size_t)ik * NCLS + lane];
    }
    const float logit = acc + b2v;
    float m = logit;
#pragma unroll
    for (int off = 1; off < 64; off <<= 1) m = fmaxf(m, __shfl_xor(m, off));
    const float e = expf(logit - m);
    float ssum = e;
#pragma unroll
    for (int off = 1; off < 64; off <<= 1) ssum += __shfl_xor(ssum, off);
    __builtin_nontemporal_store((logit - m) - logf(ssum),
                                &out[(size_t)row * NCLS + lane]);
  }
}

extern "C" void kernel_launch(void* const* d_in, const int* in_sizes, int n_in,
                              void* d_out, int out_size, void* d_ws, size_t ws_size,
                              hipStream_t stream) {
  (void)in_sizes; (void)n_in; (void)out_size; (void)ws_size;
  const float* x     = (const float*)d_in[0];
  const float* adj   = (const float*)d_in[1];
  const float* W1    = (const float*)d_in[2];
  const float* b1    = (const float*)d_in[3];
  const float* W2    = (const float*)d_in[4];
  const float* b2    = (const float*)d_in[5];
  const float* alpha = (const float*)d_in[6];

  char* ws = (char*)d_ws;
  const size_t MB = 1024 * 1024;
  bf16_t* x_bf = (bf16_t*)(ws + 0 * MB);    // 16 MB
  bf16_t* xW1  = (bf16_t*)(ws + 16 * MB);   // 16 MB
  bf16_t* W1t  = (bf16_t*)(ws + 48 * MB);   // 2 MB
  bf16_t* W2t  = (bf16_t*)(ws + 50 * MB);   // 128KB
  float*  out2 = (float*)(ws + 51 * MB);    // 2 MB
  int*    idxm = (int*)(ws + 53 * MB);      // 1 MB
  float*  wm   = (float*)(ws + 54 * MB);    // 1 MB
  bf16_t* part = (bf16_t*)(ws + 56 * MB);   // 8 MB: 8 x [8192][64] bf16 K-partials

  topk_kernel<<<dim3(N_NODES + 272), dim3(256), 0, stream>>>(
      adj, alpha, x, x_bf, idxm, wm, W1, W1t, W2, W2t);
  gemm1_kernel<<<dim3(512), dim3(256), 0, stream>>>(x_bf, W1t, xW1);
  spmm_gemm2_kernel<<<dim3((N_NODES / SROWS) * NCHUNK), dim3(256), 0, stream>>>(
      xW1, idxm, wm, b1, W2t, part);
  reduce8_kernel<<<dim3(N_NODES * NCLS / 8 / 256), dim3(256), 0, stream>>>(part, out2);
  final_kernel<<<dim3(N_NODES / 8), dim3(256), 0, stream>>>(out2, idxm, wm, b2, (float*)d_out);
}